// Round 3
// baseline (653.894 us; speedup 1.0000x reference)
//
#include <hip/hip_runtime.h>
#include <hip/hip_bf16.h>
#include <math.h>

typedef __bf16 bf16x8 __attribute__((ext_vector_type(8)));
typedef __bf16 bf16x4 __attribute__((ext_vector_type(4)));
typedef float  f32x4  __attribute__((ext_vector_type(4)));

#define S_LEN 2048
#define NB    8
#define NH    16
#define NP    8
#define DIM   1024

struct F8 { float v[8]; };

__device__ __forceinline__ void gld16(const void* g, void* l) {
  __builtin_amdgcn_global_load_lds(
      (__attribute__((address_space(1))) void*)g,
      (__attribute__((address_space(3))) void*)l, 16, 0, 0);
}

// ---------------- small prep kernels ----------------

__global__ void k_cast_bf16(const float* __restrict__ src, __bf16* __restrict__ dst, int n4) {
  int i = blockIdx.x * 256 + threadIdx.x;
  if (i >= n4) return;
  float4 v = reinterpret_cast<const float4*>(src)[i];
  bf16x4 o;
  o.x = (__bf16)v.x; o.y = (__bf16)v.y; o.z = (__bf16)v.z; o.w = (__bf16)v.w;
  reinterpret_cast<bf16x4*>(dst)[i] = o;
}

// all weight transposes in one launch; y selects the matrix
__global__ __launch_bounds__(256) void k_pack_all(
    const float* __restrict__ Wq, const float* __restrict__ Wk, const float* __restrict__ Wv,
    const float* __restrict__ Wt, const float* __restrict__ Wo,
    const float* __restrict__ Woff, const float* __restrict__ Wps,
    __bf16* __restrict__ wcat, __bf16* __restrict__ wot, __bf16* __restrict__ w2t) {
  const int y = blockIdx.y;
  const float* W; __bf16* dst; int N = 1024;
  switch (y) {
    case 0: W = Wq;   dst = wcat;            break;
    case 1: W = Wk;   dst = wcat + 1048576;  break;
    case 2: W = Wv;   dst = wcat + 2097152;  break;
    case 3: W = Wt;   dst = wcat + 3145728;  break;
    case 4: W = Wo;   dst = wot;             break;
    case 5: W = Woff; dst = w2t;            N = 128; break;
    default: W = Wps; dst = w2t + 131072;   N = 128; break;
  }
  const int K = 1024;
  const int ntn = N >> 6;
  const int nblk = (K >> 6) * ntn;
  if (blockIdx.x >= nblk) return;
  __shared__ float t[64][65];
  const int bk = blockIdx.x / ntn, bn = blockIdx.x - bk * ntn;
  const int tid = threadIdx.x;
  const int c4 = tid & 15;
  const int r0 = tid >> 4;
#pragma unroll
  for (int rp = 0; rp < 4; ++rp) {
    const int row = rp * 16 + r0;
    float4 v = *(const float4*)(W + (size_t)(bk * 64 + row) * N + bn * 64 + c4 * 4);
    t[row][c4 * 4 + 0] = v.x; t[row][c4 * 4 + 1] = v.y;
    t[row][c4 * 4 + 2] = v.z; t[row][c4 * 4 + 3] = v.w;
  }
  __syncthreads();
  const int n = tid >> 2, q = tid & 3;
  bf16x8 o0, o1;
#pragma unroll
  for (int j = 0; j < 8; ++j) o0[j] = (__bf16)t[q * 16 + j][n];
#pragma unroll
  for (int j = 0; j < 8; ++j) o1[j] = (__bf16)t[q * 16 + 8 + j][n];
  __bf16* dp = dst + (size_t)(bn * 64 + n) * K + bk * 64 + q * 16;
  *(bf16x8*)dp = o0;
  *(bf16x8*)(dp + 8) = o1;
}

__global__ void k_ebias(const float* __restrict__ bq, const float* __restrict__ bk,
                        const float* __restrict__ bv, float* __restrict__ ebias) {
  int i = blockIdx.x * 256 + threadIdx.x;
  if (i >= 3072) return;
  const float* src = (i < 1024) ? bq : (i < 2048) ? bk : bv;
  ebias[i] = src[i & 1023];
}

__global__ void k_precompute(const float* __restrict__ Wc, const float* __restrict__ bc,
                             const float* __restrict__ Eb, const float* __restrict__ Wt,
                             const float* __restrict__ bt,
                             float* __restrict__ wc_t, float* __restrict__ ebt,
                             float* __restrict__ biasp) {
  int d = blockIdx.x * 256 + threadIdx.x;
  if (d >= 1024) return;
  float accW = 0.f, accB = 0.f;
  for (int f = 0; f < 256; ++f) {
    float wt2 = Wt[(size_t)(1024 + f) * 1024 + d];
    accW += Wc[f] * wt2;
    accB += bc[f] * wt2;
  }
  wc_t[d] = accW;
  biasp[d] = bt[d] + accB;
  for (int j = 0; j < 9; ++j) {
    float a = 0.f;
    for (int f = 0; f < 256; ++f)
      a += Eb[j * 256 + f] * Wt[(size_t)(1280 + f) * 1024 + d];
    ebt[j * 1024 + d] = a;
  }
}

__global__ void k_rowfeat(const float* __restrict__ td, float* __restrict__ dl,
                          int* __restrict__ bucket, int n) {
  int i = blockIdx.x * 256 + threadIdx.x;
  if (i >= n) return;
  float dt = fmaxf(td[i], 0.f);
  dl[i] = log1pf(dt);
  const float B0[8] = {0.f, 0.5f, 1.f, 2.f, 4.f, 8.f, 12.f, 24.f};
  int bk = 0;
#pragma unroll
  for (int j = 0; j < 8; ++j) bk += (B0[j] < dt) ? 1 : 0;
  bucket[i] = bk;
}

__global__ void k_cumsum(const float* __restrict__ td, float* __restrict__ el) {
  __shared__ float part[256];
  __shared__ float pre[256];
  int b = blockIdx.x, t = threadIdx.x;
  const float* x = td + b * S_LEN;
  float* o = el + b * S_LEN;
  float loc[8];
  float run = 0.f;
#pragma unroll
  for (int j = 0; j < 8; ++j) { run += fmaxf(x[t * 8 + j], 0.f); loc[j] = run; }
  part[t] = run;
  __syncthreads();
  if (t == 0) {
    float acc = 0.f;
    for (int i = 0; i < 256; ++i) { pre[i] = acc; acc += part[i]; }
  }
  __syncthreads();
  float base = pre[t];
#pragma unroll
  for (int j = 0; j < 8; ++j) o[t * 8 + j] = base + loc[j];
}

// ---------------- GEMM params ----------------

struct GP {
  const __bf16* A; const __bf16* Bt;
  int M, N, K;
  __bf16 *qb, *kb, *vb, *ctxb;
  const float *ebias, *biasp, *wc_t, *ebt, *dl;
  const int* bucket;
  float *offa, *psa;
  const float *boff, *bps;
  float* outp; const float* bo;
};

// ---------------- GEMM 256x256, BK=32, 8 waves, TRIPLE-buffer + counted vmcnt (T3/T4/T5) ----
// Schedule per K-tile t:
//   s_waitcnt vmcnt(4)  (tile t landed; tile t+1's 4 loads stay in flight)
//   s_barrier           (raw: no compiler vmcnt(0) drain)
//   STAGE(t+2) -> buf[(t+2)%3]   (that buffer's reads finished in loop t-1, ordered by barrier)
//   12 x ds_read_b128; setprio(1); 32 MFMA; setprio(0)
// Swizzle: 64B rows, 16B slot ^= (row>>1)&3 on both stage-source and ds_read (rule #21).
// Computes C^T fragments (swapped MFMA operands) -> vectorized row-major epilogue.

template <int MODE>
__global__ __launch_bounds__(512, 2) void k_gemm2(GP pr) {
  __shared__ __align__(16) __bf16 As[3][256 * 32];
  __shared__ __align__(16) __bf16 Bs[3][256 * 32];
  const int tid = threadIdx.x;
  const int wave = tid >> 6, lane = tid & 63;
  const int wm = wave >> 2, wn = wave & 3;      // 2 x 4 wave grid, wave tile 128(M) x 64(N)
  const int rA = lane & 15, rG = lane >> 4;

  // XCD-aware bijective swizzle (nwg % 8 == 0 for all our grids)
  const int nwg = gridDim.x;
  const int cpx = nwg >> 3;
  const int wg = (blockIdx.x & 7) * cpx + (blockIdx.x >> 3);

  const int nbn = pr.N >> 8;
  const int bm = wg / nbn, bn = wg - bm * nbn;
  const int m0 = bm << 8, n0 = bn << 8;
  const int K = pr.K;
  const int NT = K >> 5;

  // staging: 512 threads x 16B covers 128 rows x 64B; two passes (rows 0-127 / 128-255)
  const int srow = wave * 16 + (lane >> 2);
  const int scs = ((lane & 3) ^ ((lane >> 3) & 3)) << 3;  // swizzled element col in [0,32)
  const int stgoff = wave * 1024 + lane * 16;

  const __bf16* Arow0 = pr.A  + (size_t)(m0 + srow) * K;
  const __bf16* Arow1 = pr.A  + (size_t)(m0 + 128 + srow) * K;
  const __bf16* Brow0 = pr.Bt + (size_t)(n0 + srow) * K;
  const __bf16* Brow1 = pr.Bt + (size_t)(n0 + 128 + srow) * K;

#define STAGE(tt, bi) do {                                   \
    const int c_ = ((tt) << 5) + scs;                        \
    gld16(Arow0 + c_, (char*)As[bi] + stgoff);               \
    gld16(Arow1 + c_, (char*)As[bi] + 8192 + stgoff);        \
    gld16(Brow0 + c_, (char*)Bs[bi] + stgoff);               \
    gld16(Brow1 + c_, (char*)Bs[bi] + 8192 + stgoff);        \
  } while (0)

  f32x4 acc[8][4] = {};

  // fragment read bases: slot is lane-constant across mt/nt
  const int slot = (rG ^ ((rA >> 1) & 3)) << 4;
  const int aoff = wm * 8192 + rA * 64 + slot;
  const int boff = wn * 4096 + rA * 64 + slot;

  // prologue: stage tiles 0 and 1
  STAGE(0, 0);
  STAGE(1, 1);

  int b0 = 0, b1 = 1, b2 = 2;
  for (int t = 0; t < NT; ++t) {
    if (t == NT - 1) asm volatile("s_waitcnt vmcnt(0)" ::: "memory");
    else             asm volatile("s_waitcnt vmcnt(4)" ::: "memory");
    __builtin_amdgcn_s_barrier();
    if (t + 2 < NT) STAGE(t + 2, b2);

    const char* Ab = (const char*)As[b0] + aoff;
    const char* Bb = (const char*)Bs[b0] + boff;
    bf16x8 af[8], bfv[4];
#pragma unroll
    for (int mt = 0; mt < 8; ++mt) af[mt] = *(const bf16x8*)(Ab + mt * 1024);
#pragma unroll
    for (int nt = 0; nt < 4; ++nt) bfv[nt] = *(const bf16x8*)(Bb + nt * 1024);
    __builtin_amdgcn_s_setprio(1);
#pragma unroll
    for (int mt = 0; mt < 8; ++mt)
#pragma unroll
      for (int nt = 0; nt < 4; ++nt)
        acc[mt][nt] = __builtin_amdgcn_mfma_f32_16x16x32_bf16(bfv[nt], af[mt], acc[mt][nt], 0, 0, 0);
    __builtin_amdgcn_s_setprio(0);

    const int tmp = b0; b0 = b1; b1 = b2; b2 = tmp;
  }
#undef STAGE

  // epilogue: acc = C^T frag; lane owns row gr, 4 consecutive cols per nt
#pragma unroll
  for (int mt = 0; mt < 8; ++mt) {
    const int gr = m0 + wm * 128 + mt * 16 + rA;   // M index (b*2048+s)
    if constexpr (MODE == 0) {
      const int seg = n0 >> 10;
      const int dbase = n0 & 1023;
      __bf16* dst = (seg == 0) ? pr.qb : (seg == 1) ? pr.kb : (seg == 2) ? pr.vb : pr.ctxb;
      const bool isCtx = (seg == 3);
      const float dlv = isCtx ? pr.dl[gr] : 0.f;
      const int bkt = isCtx ? pr.bucket[gr] : 0;
      __bf16* rowp = dst + (size_t)gr * 1024;
#pragma unroll
      for (int nt = 0; nt < 4; ++nt) {
        const int d0 = dbase + wn * 64 + nt * 16 + rG * 4;
        bf16x4 o;
#pragma unroll
        for (int i = 0; i < 4; ++i) {
          const int d = d0 + i;
          float v = acc[mt][nt][i];
          if (isCtx) v += pr.biasp[d] + dlv * pr.wc_t[d] + pr.ebt[bkt * 1024 + d];
          else       v += pr.ebias[seg * 1024 + d];
          o[i] = (__bf16)v;
        }
        *(bf16x4*)(rowp + d0) = o;
      }
    } else {  // MODE == 2: f32 out + bo
      float* rowp = pr.outp + (size_t)gr * 1024;
#pragma unroll
      for (int nt = 0; nt < 4; ++nt) {
        const int d0 = n0 + wn * 64 + nt * 16 + rG * 4;
        f32x4 o;
#pragma unroll
        for (int i = 0; i < 4; ++i) o[i] = acc[mt][nt][i] + pr.bo[d0 + i];
        *(f32x4*)(rowp + d0) = o;
      }
    }
  }
}

// ---------------- GEMM 128x128 (m97 structure) for the small-N G2 ----------------

__global__ __launch_bounds__(256) void k_gemm1(GP pr) {
  __shared__ __bf16 As[128 * 32];
  __shared__ __bf16 Bs[128 * 32];
  const int tid = threadIdx.x;
  const int wave = tid >> 6, lane = tid & 63;
  const int wm = wave >> 1, wn = wave & 1;
  const int nbn = pr.N >> 7;
  const int bm = blockIdx.x / nbn, bn = blockIdx.x - bm * nbn;
  const int m0 = bm << 7, n0 = bn << 7;
  const int K = pr.K;
  const int rA = lane & 15, rG = lane >> 4;

  f32x4 acc[4][4] = {};

  for (int k0 = 0; k0 < K; k0 += 32) {
#pragma unroll
    for (int ch = 0; ch < 2; ++ch) {
      const int fb = ch * 4096 + wave * 1024;
      const int e = (fb >> 1) + lane * 8;
      const int row = e >> 5, col = e & 31;
      gld16(pr.A  + (size_t)(m0 + row) * K + (k0 + col), (char*)As + fb);
      gld16(pr.Bt + (size_t)(n0 + row) * K + (k0 + col), (char*)Bs + fb);
    }
    __syncthreads();

    bf16x8 af[4], bfv[4];
#pragma unroll
    for (int mt = 0; mt < 4; ++mt)
      af[mt] = *(const bf16x8*)&As[(wm * 64 + mt * 16 + rA) * 32 + rG * 8];
#pragma unroll
    for (int nt = 0; nt < 4; ++nt)
      bfv[nt] = *(const bf16x8*)&Bs[(wn * 64 + nt * 16 + rA) * 32 + rG * 8];
#pragma unroll
    for (int mt = 0; mt < 4; ++mt)
#pragma unroll
      for (int nt = 0; nt < 4; ++nt)
        acc[mt][nt] = __builtin_amdgcn_mfma_f32_16x16x32_bf16(af[mt], bfv[nt], acc[mt][nt], 0, 0, 0);
    __syncthreads();
  }

  // MODE 1 epilogue (C layout: col = lane&15, row = (lane>>4)*4 + i)
#pragma unroll
  for (int mt = 0; mt < 4; ++mt) {
#pragma unroll
    for (int nt = 0; nt < 4; ++nt) {
      const int gc = n0 + wn * 64 + nt * 16 + rA;
      const int grb = m0 + wm * 64 + mt * 16 + rG * 4;
#pragma unroll
      for (int i = 0; i < 4; ++i) {
        const int gr = grb + i;
        float val = acc[mt][nt][i];
        const int bb = gr >> 11, ss = gr & 2047;
        const int half = gc >> 7, j = gc & 127;
        const int hh = j >> 3, pp = j & 7;
        size_t di = (((size_t)bb * NH + hh) * S_LEN + ss) * NP + pp;
        if (half == 0) pr.offa[di] = tanhf(val + pr.boff[j]);
        else           pr.psa[di]  = val + pr.bps[j];
      }
    }
  }
}

// ---------------- deformable attention: one wave per (b,h,s); q/k/v in [B,S,D] ----------------

__global__ __launch_bounds__(256) void k_attn(
    const __bf16* __restrict__ qb, const __bf16* __restrict__ kb, const __bf16* __restrict__ vb,
    const float* __restrict__ offa, const float* __restrict__ psa,
    const float* __restrict__ elapsed,
    const float* __restrict__ point_bias, const float* __restrict__ tdw,
    const float* __restrict__ tdb,
    __bf16* __restrict__ attn_out, F8 anchors) {
  const int wid = blockIdx.x * 4 + (threadIdx.x >> 6);
  const int lane = threadIdx.x & 63;
  const int s = wid & (S_LEN - 1);
  const int h = (wid >> 11) & (NH - 1);
  const int b = wid >> 15;
  const int p = lane >> 3, c = lane & 7;

  const float anchor = anchors.v[p];

  const size_t bBase = (size_t)b * S_LEN;
  const size_t ppos = (((size_t)b * NH + h) * S_LEN + s) * NP + p;
  const float off = offa[ppos];
  const float psv = psa[ppos];

  float pos = (float)s - anchor + off * 8.0f;
  pos = fminf(fmaxf(pos, 0.0f), (float)s);
  int li = (int)pos; if (li > S_LEN - 1) li = S_LEN - 1;
  const float alpha = pos - (float)li;
  int ri = li + 1; if (ri > S_LEN - 1) ri = S_LEN - 1;

  const int hd = h * 64 + c * 8;
  const bf16x8 qv = *(const bf16x8*)(qb + (bBase + s) * DIM + hd);
  const bf16x8 kl = *(const bf16x8*)(kb + (bBase + li) * DIM + hd);
  const bf16x8 kr = *(const bf16x8*)(kb + (bBase + ri) * DIM + hd);

  float dot = 0.f;
#pragma unroll
  for (int j = 0; j < 8; ++j) {
    float klj = (float)kl[j];
    float kf = klj + alpha * ((float)kr[j] - klj);
    dot += (float)qv[j] * kf;
  }
  dot += __shfl_xor(dot, 1);
  dot += __shfl_xor(dot, 2);
  dot += __shfl_xor(dot, 4);

  const float el_s = elapsed[b * S_LEN + s];
  const float ell = elapsed[b * S_LEN + li];
  const float elr = elapsed[b * S_LEN + ri];
  const float elsamp = ell + alpha * (elr - ell);
  const float rel = log1pf(fmaxf(el_s - elsamp, 0.f));
  const int hp = h * NP + p;
  const float decay = log1pf(expf(tdw[hp]));
  float score = dot * 0.125f + psv + tdb[hp] - decay * rel + point_bias[hp];

  float m = score;
  m = fmaxf(m, __shfl_xor(m, 8));
  m = fmaxf(m, __shfl_xor(m, 16));
  m = fmaxf(m, __shfl_xor(m, 32));
  float e = expf(score - m);
  float dsum = e;
  dsum += __shfl_xor(dsum, 8);
  dsum += __shfl_xor(dsum, 16);
  dsum += __shfl_xor(dsum, 32);
  const float w = e / dsum;

  const bf16x8 vl = *(const bf16x8*)(vb + (bBase + li) * DIM + hd);
  const bf16x8 vr = *(const bf16x8*)(vb + (bBase + ri) * DIM + hd);
  float o[8];
#pragma unroll
  for (int j = 0; j < 8; ++j) {
    float vlj = (float)vl[j];
    float vf = vlj + alpha * ((float)vr[j] - vlj);
    o[j] = w * vf;
  }
#pragma unroll
  for (int j = 0; j < 8; ++j) {
    o[j] += __shfl_xor(o[j], 8);
    o[j] += __shfl_xor(o[j], 16);
    o[j] += __shfl_xor(o[j], 32);
  }
  if (p == 0) {
    bf16x8 ov;
#pragma unroll
    for (int j = 0; j < 8; ++j) ov[j] = (__bf16)o[j];
    *(bf16x8*)(attn_out + ((size_t)b * S_LEN + s) * DIM + h * 64 + c * 8) = ov;
  }
}

// ---------------- host ----------------

extern "C" void kernel_launch(void* const* d_in, const int* in_sizes, int n_in,
                              void* d_out, int out_size, void* d_ws, size_t ws_size,
                              hipStream_t stream) {
  const float* x    = (const float*)d_in[0];
  const float* td   = (const float*)d_in[1];
  const float* Wq   = (const float*)d_in[2];
  const float* bq   = (const float*)d_in[3];
  const float* Wk   = (const float*)d_in[4];
  const float* bk   = (const float*)d_in[5];
  const float* Wv   = (const float*)d_in[6];
  const float* bv   = (const float*)d_in[7];
  const float* Wc   = (const float*)d_in[8];
  const float* bc   = (const float*)d_in[9];
  const float* Eb   = (const float*)d_in[10];
  const float* Wt   = (const float*)d_in[11];
  const float* bt   = (const float*)d_in[12];
  const float* Woff = (const float*)d_in[13];
  const float* boff = (const float*)d_in[14];
  const float* Wps  = (const float*)d_in[15];
  const float* bps  = (const float*)d_in[16];
  const float* Wo   = (const float*)d_in[17];
  const float* bo   = (const float*)d_in[18];
  const float* pb   = (const float*)d_in[19];
  const float* tdw  = (const float*)d_in[20];
  const float* tdb  = (const float*)d_in[21];

  char* w = (char*)d_ws;
  size_t off = 0;
  auto take = [&](size_t n) {
    char* pp = w + off;
    off += (n + 255) & ~(size_t)255;
    return pp;
  };
  __bf16* xb    = (__bf16*)take(33554432);  // x bf16 [16384,1024]; reused as attn_out
  __bf16* wcat  = (__bf16*)take(8388608);   // [4096,1024] B^T of Wq|Wk|Wv|Wt1
  __bf16* w2t   = (__bf16*)take(524288);    // [256,1024] B^T of Woff|Wps
  __bf16* wot   = (__bf16*)take(2097152);   // [1024,1024] B^T of Wo
  __bf16* qb    = (__bf16*)take(33554432);  // [B,S,D]
  __bf16* kb    = (__bf16*)take(33554432);
  __bf16* vb    = (__bf16*)take(33554432);
  __bf16* ctxb  = (__bf16*)take(33554432);  // [16384,1024]
  float* offa   = (float*)take(8388608);    // [B,H,S,P]
  float* psa    = (float*)take(8388608);
  float* elap   = (float*)take(65536);
  float* dl     = (float*)take(65536);
  int*   bucket = (int*)take(65536);
  float* wc_t   = (float*)take(4096);
  float* ebt    = (float*)take(36864);
  float* biasp  = (float*)take(4096);
  float* ebias  = (float*)take(12288);
  if (off > ws_size) return;
  __bf16* attn_out = xb;  // alias: xb dead after G1

  F8 anc;
  {
    const double step = log2(129.0) / 7.0;
    anc.v[0] = 0.0f;
    for (int p = 1; p < 8; ++p) anc.v[p] = (float)(exp2((double)p * step) - 1.0);
  }

  k_cast_bf16<<<16384, 256, 0, stream>>>(x, xb, 4194304);
  k_pack_all<<<dim3(256, 7), 256, 0, stream>>>(Wq, Wk, Wv, Wt, Wo, Woff, Wps, wcat, wot, w2t);
  k_ebias<<<12, 256, 0, stream>>>(bq, bk, bv, ebias);
  k_precompute<<<4, 256, 0, stream>>>(Wc, bc, Eb, Wt, bt, wc_t, ebt, biasp);
  k_rowfeat<<<64, 256, 0, stream>>>(td, dl, bucket, 16384);
  k_cumsum<<<8, 256, 0, stream>>>(td, elap);

  GP g1 = {};
  g1.A = xb; g1.Bt = wcat; g1.M = 16384; g1.N = 4096; g1.K = 1024;
  g1.qb = qb; g1.kb = kb; g1.vb = vb; g1.ctxb = ctxb;
  g1.ebias = ebias; g1.biasp = biasp; g1.wc_t = wc_t; g1.ebt = ebt;
  g1.dl = dl; g1.bucket = bucket;
  k_gemm2<0><<<64 * 16, 512, 0, stream>>>(g1);

  GP g2 = {};
  g2.A = ctxb; g2.Bt = w2t; g2.M = 16384; g2.N = 256; g2.K = 1024;
  g2.offa = offa; g2.psa = psa; g2.boff = boff; g2.bps = bps;
  k_gemm1<<<128 * 2, 256, 0, stream>>>(g2);

  k_attn<<<65536, 256, 0, stream>>>(qb, kb, vb, offa, psa, elap, pb, tdw, tdb, attn_out, anc);

  GP g3 = {};
  g3.A = attn_out; g3.Bt = wot; g3.M = 16384; g3.N = 1024; g3.K = 1024;
  g3.outp = (float*)d_out; g3.bo = bo;
  k_gemm2<2><<<64 * 4, 512, 0, stream>>>(g3);
}

// Round 4
// 560.495 us; speedup vs baseline: 1.1666x; 1.1666x over previous
//
#include <hip/hip_runtime.h>
#include <hip/hip_bf16.h>
#include <math.h>

typedef __bf16 bf16x8 __attribute__((ext_vector_type(8)));
typedef __bf16 bf16x4 __attribute__((ext_vector_type(4)));
typedef float  f32x4  __attribute__((ext_vector_type(4)));

#define S_LEN 2048
#define NB    8
#define NH    16
#define NP    8
#define DIM   1024

struct F8 { float v[8]; };

__device__ __forceinline__ void gld16(const void* g, void* l) {
  __builtin_amdgcn_global_load_lds(
      (__attribute__((address_space(1))) void*)g,
      (__attribute__((address_space(3))) void*)l, 16, 0, 0);
}

// ---------------- prep kernels ----------------

// casts x (4194304 float4) and Wt rows 0..1023 (262144 float4) to bf16
__global__ void k_cast2(const float* __restrict__ x, __bf16* __restrict__ xb,
                        const float* __restrict__ wt, __bf16* __restrict__ wt1b) {
  int i = blockIdx.x * 256 + threadIdx.x;
  const float* src; __bf16* dst;
  if (i < 4194304) { src = x; dst = xb; }
  else { i -= 4194304; if (i >= 262144) return; src = wt; dst = wt1b; }
  float4 v = reinterpret_cast<const float4*>(src)[i];
  bf16x4 o;
  o.x = (__bf16)v.x; o.y = (__bf16)v.y; o.z = (__bf16)v.z; o.w = (__bf16)v.w;
  reinterpret_cast<bf16x4*>(dst)[i] = o;
}

// all weight transposes in one launch; y selects the matrix
__global__ __launch_bounds__(256) void k_pack_all(
    const float* __restrict__ Wq, const float* __restrict__ Wk, const float* __restrict__ Wv,
    const float* __restrict__ Wo, const float* __restrict__ Woff, const float* __restrict__ Wps,
    __bf16* __restrict__ wcat, __bf16* __restrict__ wot, __bf16* __restrict__ w2t) {
  const int y = blockIdx.y;
  const float* W; __bf16* dst; int N = 1024;
  switch (y) {
    case 0: W = Wq;   dst = wcat;            break;
    case 1: W = Wk;   dst = wcat + 1048576;  break;
    case 2: W = Wv;   dst = wcat + 2097152;  break;
    case 3: W = Wo;   dst = wot;             break;
    case 4: W = Woff; dst = w2t;            N = 128; break;
    default: W = Wps; dst = w2t + 131072;   N = 128; break;
  }
  const int K = 1024;
  const int ntn = N >> 6;
  const int nblk = (K >> 6) * ntn;
  if (blockIdx.x >= nblk) return;
  __shared__ float t[64][65];
  const int bk = blockIdx.x / ntn, bn = blockIdx.x - bk * ntn;
  const int tid = threadIdx.x;
  const int c4 = tid & 15;
  const int r0 = tid >> 4;
#pragma unroll
  for (int rp = 0; rp < 4; ++rp) {
    const int row = rp * 16 + r0;
    float4 v = *(const float4*)(W + (size_t)(bk * 64 + row) * N + bn * 64 + c4 * 4);
    t[row][c4 * 4 + 0] = v.x; t[row][c4 * 4 + 1] = v.y;
    t[row][c4 * 4 + 2] = v.z; t[row][c4 * 4 + 3] = v.w;
  }
  __syncthreads();
  const int n = tid >> 2, q = tid & 3;
  bf16x8 o0, o1;
#pragma unroll
  for (int j = 0; j < 8; ++j) o0[j] = (__bf16)t[q * 16 + j][n];
#pragma unroll
  for (int j = 0; j < 8; ++j) o1[j] = (__bf16)t[q * 16 + 8 + j][n];
  __bf16* dp = dst + (size_t)(bn * 64 + n) * K + bk * 64 + q * 16;
  *(bf16x8*)dp = o0;
  *(bf16x8*)(dp + 8) = o1;
}

// merged small prep: blocks 0-3 -> wc_t/biasp/ebt ; 4-15 -> ebias ; 16 -> dec/pbias
__global__ void k_prep(const float* __restrict__ Wc, const float* __restrict__ bc,
                       const float* __restrict__ Eb, const float* __restrict__ Wt,
                       const float* __restrict__ bt,
                       const float* __restrict__ bq, const float* __restrict__ bk,
                       const float* __restrict__ bv,
                       const float* __restrict__ tdw, const float* __restrict__ tdb,
                       const float* __restrict__ point_bias,
                       float* __restrict__ wc_t, float* __restrict__ ebt,
                       float* __restrict__ biasp, float* __restrict__ ebias,
                       float* __restrict__ dec, float* __restrict__ pbias) {
  const int blk = blockIdx.x, tid = threadIdx.x;
  if (blk < 4) {
    const int d = blk * 256 + tid;
    float accW = 0.f, accB = 0.f;
    for (int f = 0; f < 256; ++f) {
      float wt2 = Wt[(size_t)(1024 + f) * 1024 + d];
      accW += Wc[f] * wt2;
      accB += bc[f] * wt2;
    }
    wc_t[d] = accW;
    biasp[d] = bt[d] + accB;
    for (int j = 0; j < 9; ++j) {
      float a = 0.f;
      for (int f = 0; f < 256; ++f)
        a += Eb[j * 256 + f] * Wt[(size_t)(1280 + f) * 1024 + d];
      ebt[j * 1024 + d] = a;
    }
  } else if (blk < 16) {
    const int i = (blk - 4) * 256 + tid;
    const float* src = (i < 1024) ? bq : (i < 2048) ? bk : bv;
    ebias[i] = src[i & 1023];
  } else {
    if (tid < 128) {
      dec[tid] = log1pf(expf(tdw[tid]));
      pbias[tid] = tdb[tid] + point_bias[tid];
    }
  }
}

// second-stage: cw2[j], bo2[j], ebo[9][256] (j over combined [Woff|Wps] cols)
__global__ void k_prep2(const float* __restrict__ wc_t, const float* __restrict__ biasp,
                        const float* __restrict__ ebt,
                        const float* __restrict__ Woff, const float* __restrict__ Wps,
                        const float* __restrict__ boff, const float* __restrict__ bps,
                        float* __restrict__ cw2, float* __restrict__ bo2,
                        float* __restrict__ ebo) {
  const int t = blockIdx.x, j = threadIdx.x;   // 11 blocks x 256 threads
  const float* vec = (t == 0) ? wc_t : (t == 1) ? biasp : ebt + (t - 2) * 1024;
  const float* W2 = (j < 128) ? (Woff + j) : (Wps + j - 128);
  float acc = 0.f;
  for (int d = 0; d < 1024; ++d) acc += vec[d] * W2[d * 128];
  if (t == 0)      cw2[j] = acc;
  else if (t == 1) bo2[j] = acc + ((j < 128) ? boff[j] : bps[j - 128]);
  else             ebo[(t - 2) * 256 + j] = acc;
}

// per-batch: dl, bucket, causal-relu cumsum
__global__ void k_rowcum(const float* __restrict__ td, float* __restrict__ dl,
                         int* __restrict__ bucket, float* __restrict__ el) {
  __shared__ float part[256];
  __shared__ float pre[256];
  const int b = blockIdx.x, t = threadIdx.x;
  const float* x = td + b * S_LEN;
  float* o = el + b * S_LEN;
  const float B0[8] = {0.f, 0.5f, 1.f, 2.f, 4.f, 8.f, 12.f, 24.f};
  float loc[8];
  float run = 0.f;
#pragma unroll
  for (int j = 0; j < 8; ++j) {
    const int i = t * 8 + j;
    float dt = fmaxf(x[i], 0.f);
    dl[b * S_LEN + i] = log1pf(dt);
    int bk = 0;
#pragma unroll
    for (int q = 0; q < 8; ++q) bk += (B0[q] < dt) ? 1 : 0;
    bucket[b * S_LEN + i] = bk;
    run += dt; loc[j] = run;
  }
  part[t] = run;
  __syncthreads();
  if (t == 0) {
    float acc = 0.f;
    for (int i = 0; i < 256; ++i) { pre[i] = acc; acc += part[i]; }
  }
  __syncthreads();
  float base = pre[t];
#pragma unroll
  for (int j = 0; j < 8; ++j) o[t * 8 + j] = base + loc[j];
}

// ---------------- GEMM params ----------------

struct GP {
  const __bf16* A; const __bf16* Bt;
  int M, N, K;
  __bf16 *qb, *kb, *vb;
  const float *ebias, *cw2, *ebo, *bo2, *dl;
  const int* bucket;
  float *offa, *psa;
  float* outp; const float* bo;
};

// ---------------- GEMM 256x256, BK=64, 8 waves, 2-phase dbuf (R2-proven) + T2 swizzle ----
// Computes C^T fragments (swapped MFMA operands) so each lane owns 4 consecutive
// output columns of one row -> vectorized epilogue stores.

template <int MODE>
__global__ __launch_bounds__(512, 2) void k_gemm2(GP pr) {
  __shared__ __align__(16) __bf16 As[2][256 * 64];
  __shared__ __align__(16) __bf16 Bs[2][256 * 64];
  const int tid = threadIdx.x;
  const int wave = tid >> 6, lane = tid & 63;
  const int wm = wave >> 2, wn = wave & 3;      // 2 x 4 wave grid, wave tile 128(M) x 64(N)
  const int rA = lane & 15, rG = lane >> 4;

  // XCD-aware bijective swizzle (nwg % 8 == 0 for all our grids)
  const int nwg = gridDim.x;
  const int cpx = nwg >> 3;
  const int wg = (blockIdx.x & 7) * cpx + (blockIdx.x >> 3);

  const int nbn = pr.N >> 8;
  const int bm = wg / nbn, bn = wg - bm * nbn;
  const int m0 = bm << 8, n0 = bn << 8;
  const int K = pr.K;
  const int NT = K >> 6;

  // staging geometry: 512 threads x 16B x 4 passes = 32KB/tile
  const int srow = wave * 8 + (lane >> 3);      // + r*64
  const int sslot = lane & 7;

  f32x4 acc[8][4] = {};

  // prologue: stage tile 0 into buf 0
#pragma unroll
  for (int r = 0; r < 4; ++r) {
    const int row = r * 64 + srow;
    const int fb = r * 8192 + wave * 1024;
    const int col = (sslot ^ (row & 7)) << 3;
    gld16(pr.A  + (size_t)(m0 + row) * K + col, (char*)As[0] + fb);
    gld16(pr.Bt + (size_t)(n0 + row) * K + col, (char*)Bs[0] + fb);
  }
  __syncthreads();

  int buf = 0;
  for (int t = 0; t < NT; ++t) {
    if (t + 1 < NT) {
      const int k0 = (t + 1) << 6;
#pragma unroll
      for (int r = 0; r < 4; ++r) {
        const int row = r * 64 + srow;
        const int fb = r * 8192 + wave * 1024;
        const int col = k0 + ((sslot ^ (row & 7)) << 3);
        gld16(pr.A  + (size_t)(m0 + row) * K + col, (char*)As[buf ^ 1] + fb);
        gld16(pr.Bt + (size_t)(n0 + row) * K + col, (char*)Bs[buf ^ 1] + fb);
      }
    }
#pragma unroll
    for (int kk = 0; kk < 2; ++kk) {
      bf16x8 af[8], bfv[4];
#pragma unroll
      for (int mt = 0; mt < 8; ++mt) {
        const int row = wm * 128 + mt * 16 + rA;
        const int slot = ((kk * 4 + rG) ^ (row & 7)) << 4;
        af[mt] = *(const bf16x8*)((const char*)As[buf] + row * 128 + slot);
      }
#pragma unroll
      for (int nt = 0; nt < 4; ++nt) {
        const int row = wn * 64 + nt * 16 + rA;
        const int slot = ((kk * 4 + rG) ^ (row & 7)) << 4;
        bfv[nt] = *(const bf16x8*)((const char*)Bs[buf] + row * 128 + slot);
      }
#pragma unroll
      for (int mt = 0; mt < 8; ++mt)
#pragma unroll
        for (int nt = 0; nt < 4; ++nt)
          acc[mt][nt] = __builtin_amdgcn_mfma_f32_16x16x32_bf16(bfv[nt], af[mt], acc[mt][nt], 0, 0, 0);
    }
    __syncthreads();
    buf ^= 1;
  }

  // epilogue: acc = C^T frag; lane owns row gr, 4 consecutive cols per nt
#pragma unroll
  for (int mt = 0; mt < 8; ++mt) {
    const int gr = m0 + wm * 128 + mt * 16 + rA;   // M index (b*2048+s)
    if constexpr (MODE == 0) {
      const int seg = n0 >> 10;                     // 0,1,2 = q,k,v ; 3 = combined off|ps
      if (seg < 3) {
        __bf16* dst = (seg == 0) ? pr.qb : (seg == 1) ? pr.kb : pr.vb;
        const int dbase = n0 & 1023;
        __bf16* rowp = dst + (size_t)gr * 1024;
#pragma unroll
        for (int nt = 0; nt < 4; ++nt) {
          const int d0 = dbase + wn * 64 + nt * 16 + rG * 4;
          bf16x4 o;
#pragma unroll
          for (int i = 0; i < 4; ++i)
            o[i] = (__bf16)(acc[mt][nt][i] + pr.ebias[(seg << 10) + d0 + i]);
          *(bf16x4*)(rowp + d0) = o;
        }
      } else {
        const float dlv = pr.dl[gr];
        const int bkt = pr.bucket[gr];
        const int bb = gr >> 11, ss = gr & 2047;
#pragma unroll
        for (int nt = 0; nt < 4; ++nt) {
          const int j0 = wn * 64 + nt * 16 + rG * 4;
#pragma unroll
          for (int i = 0; i < 4; ++i) {
            const int j = j0 + i;
            float v = acc[mt][nt][i] + dlv * pr.cw2[j] + pr.ebo[bkt * 256 + j] + pr.bo2[j];
            if (j < 128) {
              const int hh = j >> 3, pp = j & 7;
              pr.offa[(((size_t)bb * NH + hh) * S_LEN + ss) * NP + pp] = tanhf(v);
            } else {
              const int jj = j - 128, hh = jj >> 3, pp = jj & 7;
              pr.psa[(((size_t)bb * NH + hh) * S_LEN + ss) * NP + pp] = v;
            }
          }
        }
      }
    } else {  // MODE == 2: f32 out + bo
      float* rowp = pr.outp + (size_t)gr * 1024;
#pragma unroll
      for (int nt = 0; nt < 4; ++nt) {
        const int d0 = n0 + wn * 64 + nt * 16 + rG * 4;
        f32x4 o;
#pragma unroll
        for (int i = 0; i < 4; ++i) o[i] = acc[mt][nt][i] + pr.bo[d0 + i];
        *(f32x4*)(rowp + d0) = o;
      }
    }
  }
}

// ---------------- 128x128 m97-style GEMM: combined-weight prep (bf16 out, row-major) ----

__global__ __launch_bounds__(256) void k_wcomb(GP pr) {
  __shared__ __bf16 As[128 * 32];
  __shared__ __bf16 Bs[128 * 32];
  const int tid = threadIdx.x;
  const int wave = tid >> 6, lane = tid & 63;
  const int wm = wave >> 1, wn = wave & 1;
  const int nbn = pr.N >> 7;
  const int bm = blockIdx.x / nbn, bn = blockIdx.x - bm * nbn;
  const int m0 = bm << 7, n0 = bn << 7;
  const int K = pr.K;
  const int rA = lane & 15, rG = lane >> 4;

  f32x4 acc[4][4] = {};

  for (int k0 = 0; k0 < K; k0 += 32) {
#pragma unroll
    for (int ch = 0; ch < 2; ++ch) {
      const int fb = ch * 4096 + wave * 1024;
      const int e = (fb >> 1) + lane * 8;
      const int row = e >> 5, col = e & 31;
      gld16(pr.A  + (size_t)(m0 + row) * K + (k0 + col), (char*)As + fb);
      gld16(pr.Bt + (size_t)(n0 + row) * K + (k0 + col), (char*)Bs + fb);
    }
    __syncthreads();

    bf16x8 af[4], bfv[4];
#pragma unroll
    for (int mt = 0; mt < 4; ++mt)
      af[mt] = *(const bf16x8*)&As[(wm * 64 + mt * 16 + rA) * 32 + rG * 8];
#pragma unroll
    for (int nt = 0; nt < 4; ++nt)
      bfv[nt] = *(const bf16x8*)&Bs[(wn * 64 + nt * 16 + rA) * 32 + rG * 8];
#pragma unroll
    for (int mt = 0; mt < 4; ++mt)
#pragma unroll
      for (int nt = 0; nt < 4; ++nt)
        acc[mt][nt] = __builtin_amdgcn_mfma_f32_16x16x32_bf16(af[mt], bfv[nt], acc[mt][nt], 0, 0, 0);
    __syncthreads();
  }

  // write bf16 row-major: out[gr*1024 + gc]  (C layout: col=lane&15, row=(lane>>4)*4+i)
#pragma unroll
  for (int mt = 0; mt < 4; ++mt) {
#pragma unroll
    for (int nt = 0; nt < 4; ++nt) {
      const int gc = n0 + wn * 64 + nt * 16 + rA;
      const int grb = m0 + wm * 64 + mt * 16 + rG * 4;
#pragma unroll
      for (int i = 0; i < 4; ++i)
        pr.qb[(size_t)(grb + i) * 1024 + gc] = (__bf16)acc[mt][nt][i];
    }
  }
}

// ---------------- deformable attention: one wave per (b,h,s); q/k/v in [B,S,D] ----------------

__global__ __launch_bounds__(256) void k_attn(
    const __bf16* __restrict__ qb, const __bf16* __restrict__ kb, const __bf16* __restrict__ vb,
    const float* __restrict__ offa, const float* __restrict__ psa,
    const float* __restrict__ elapsed,
    const float* __restrict__ dec, const float* __restrict__ pbias,
    __bf16* __restrict__ attn_out, F8 anchors) {
  const int wid = blockIdx.x * 4 + (threadIdx.x >> 6);
  const int lane = threadIdx.x & 63;
  const int s = wid & (S_LEN - 1);
  const int h = (wid >> 11) & (NH - 1);
  const int b = wid >> 15;
  const int p = lane >> 3, c = lane & 7;

  const float anchor = anchors.v[p];

  const size_t bBase = (size_t)b * S_LEN;
  const size_t ppos = (((size_t)b * NH + h) * S_LEN + s) * NP + p;
  const float off = offa[ppos];
  const float psv = psa[ppos];

  float pos = (float)s - anchor + off * 8.0f;
  pos = fminf(fmaxf(pos, 0.0f), (float)s);
  int li = (int)pos; if (li > S_LEN - 1) li = S_LEN - 1;
  const float alpha = pos - (float)li;
  int ri = li + 1; if (ri > S_LEN - 1) ri = S_LEN - 1;

  const int hd = h * 64 + c * 8;
  const bf16x8 qv = *(const bf16x8*)(qb + (bBase + s) * DIM + hd);
  const bf16x8 kl = *(const bf16x8*)(kb + (bBase + li) * DIM + hd);
  const bf16x8 kr = *(const bf16x8*)(kb + (bBase + ri) * DIM + hd);

  float dot = 0.f;
#pragma unroll
  for (int j = 0; j < 8; ++j) {
    float klj = (float)kl[j];
    float kf = klj + alpha * ((float)kr[j] - klj);
    dot += (float)qv[j] * kf;
  }
  dot += __shfl_xor(dot, 1);
  dot += __shfl_xor(dot, 2);
  dot += __shfl_xor(dot, 4);

  const float el_s = elapsed[b * S_LEN + s];
  const float ell = elapsed[b * S_LEN + li];
  const float elr = elapsed[b * S_LEN + ri];
  const float elsamp = ell + alpha * (elr - ell);
  const float rel = log1pf(fmaxf(el_s - elsamp, 0.f));
  const int hp = h * NP + p;
  float score = dot * 0.125f + psv + pbias[hp] - dec[hp] * rel;

  float m = score;
  m = fmaxf(m, __shfl_xor(m, 8));
  m = fmaxf(m, __shfl_xor(m, 16));
  m = fmaxf(m, __shfl_xor(m, 32));
  float e = expf(score - m);
  float dsum = e;
  dsum += __shfl_xor(dsum, 8);
  dsum += __shfl_xor(dsum, 16);
  dsum += __shfl_xor(dsum, 32);
  const float w = e / dsum;

  const bf16x8 vl = *(const bf16x8*)(vb + (bBase + li) * DIM + hd);
  const bf16x8 vr = *(const bf16x8*)(vb + (bBase + ri) * DIM + hd);
  float o[8];
#pragma unroll
  for (int j = 0; j < 8; ++j) {
    float vlj = (float)vl[j];
    float vf = vlj + alpha * ((float)vr[j] - vlj);
    o[j] = w * vf;
  }
#pragma unroll
  for (int j = 0; j < 8; ++j) {
    o[j] += __shfl_xor(o[j], 8);
    o[j] += __shfl_xor(o[j], 16);
    o[j] += __shfl_xor(o[j], 32);
  }
  if (p == 0) {
    bf16x8 ov;
#pragma unroll
    for (int j = 0; j < 8; ++j) ov[j] = (__bf16)o[j];
    *(bf16x8*)(attn_out + ((size_t)b * S_LEN + s) * DIM + h * 64 + c * 8) = ov;
  }
}

// ---------------- host ----------------

extern "C" void kernel_launch(void* const* d_in, const int* in_sizes, int n_in,
                              void* d_out, int out_size, void* d_ws, size_t ws_size,
                              hipStream_t stream) {
  const float* x    = (const float*)d_in[0];
  const float* td   = (const float*)d_in[1];
  const float* Wq   = (const float*)d_in[2];
  const float* bq   = (const float*)d_in[3];
  const float* Wk   = (const float*)d_in[4];
  const float* bk   = (const float*)d_in[5];
  const float* Wv   = (const float*)d_in[6];
  const float* bv   = (const float*)d_in[7];
  const float* Wc   = (const float*)d_in[8];
  const float* bc   = (const float*)d_in[9];
  const float* Eb   = (const float*)d_in[10];
  const float* Wt   = (const float*)d_in[11];
  const float* bt   = (const float*)d_in[12];
  const float* Woff = (const float*)d_in[13];
  const float* boff = (const float*)d_in[14];
  const float* Wps  = (const float*)d_in[15];
  const float* bps  = (const float*)d_in[16];
  const float* Wo   = (const float*)d_in[17];
  const float* bo   = (const float*)d_in[18];
  const float* pb   = (const float*)d_in[19];
  const float* tdw  = (const float*)d_in[20];
  const float* tdb  = (const float*)d_in[21];

  char* w = (char*)d_ws;
  size_t off = 0;
  auto take = [&](size_t n) {
    char* pp = w + off;
    off += (n + 255) & ~(size_t)255;
    return pp;
  };
  __bf16* xb    = (__bf16*)take(33554432);  // x bf16 [16384,1024]; reused as attn_out
  __bf16* wcat  = (__bf16*)take(8388608);   // [4096,1024]: rows 0-3071 = B^T of Wq|Wk|Wv; 3072-3327 = combined
  __bf16* w2t   = (__bf16*)take(524288);    // [256,1024] = [Woff|Wps]^T bf16
  __bf16* wot   = (__bf16*)take(2097152);   // [1024,1024] B^T of Wo
  __bf16* wt1b  = (__bf16*)take(2097152);   // [1024,1024] Wt rows 0-1023, row-major bf16
  __bf16* qb    = (__bf16*)take(33554432);  // [B,S,D]
  __bf16* kb    = (__bf16*)take(33554432);
  __bf16* vb    = (__bf16*)take(33554432);
  float* offa   = (float*)take(8388608);    // [B,H,S,P]
  float* psa    = (float*)take(8388608);
  float* elap   = (float*)take(65536);
  float* dl     = (float*)take(65536);
  int*   bucket = (int*)take(65536);
  float* wc_t   = (float*)take(4096);
  float* ebt    = (float*)take(36864);
  float* biasp  = (float*)take(4096);
  float* ebias  = (float*)take(12288);
  float* cw2    = (float*)take(1024);
  float* bo2    = (float*)take(1024);
  float* ebo    = (float*)take(9216);
  float* dec    = (float*)take(512);
  float* pbias  = (float*)take(512);
  if (off > ws_size) return;
  __bf16* attn_out = xb;  // alias: xb dead after G1

  F8 anc;
  {
    const double step = log2(129.0) / 7.0;
    anc.v[0] = 0.0f;
    for (int p = 1; p < 8; ++p) anc.v[p] = (float)(exp2((double)p * step) - 1.0);
  }

  k_cast2<<<17408, 256, 0, stream>>>(x, xb, Wt, wt1b);
  k_pack_all<<<dim3(256, 6), 256, 0, stream>>>(Wq, Wk, Wv, Wo, Woff, Wps, wcat, wot, w2t);
  k_prep<<<17, 256, 0, stream>>>(Wc, bc, Eb, Wt, bt, bq, bk, bv, tdw, tdb, pb,
                                 wc_t, ebt, biasp, ebias, dec, pbias);
  k_prep2<<<11, 256, 0, stream>>>(wc_t, biasp, ebt, Woff, Wps, boff, bps, cw2, bo2, ebo);
  k_rowcum<<<8, 256, 0, stream>>>(td, dl, bucket, elap);

  // combined weight: wcat rows 3072..3327 = (Wt1 . [Woff|Wps])^T
  GP gw = {};
  gw.A = w2t; gw.Bt = wt1b; gw.M = 256; gw.N = 1024; gw.K = 1024;
  gw.qb = wcat + 3145728;
  k_wcomb<<<16, 256, 0, stream>>>(gw);

  GP g1 = {};
  g1.A = xb; g1.Bt = wcat; g1.M = 16384; g1.N = 3328; g1.K = 1024;
  g1.qb = qb; g1.kb = kb; g1.vb = vb;
  g1.ebias = ebias; g1.cw2 = cw2; g1.ebo = ebo; g1.bo2 = bo2;
  g1.dl = dl; g1.bucket = bucket;
  g1.offa = offa; g1.psa = psa;
  k_gemm2<0><<<64 * 13, 512, 0, stream>>>(g1);

  k_attn<<<65536, 256, 0, stream>>>(qb, kb, vb, offa, psa, elap, dec, pbias, attn_out, anc);

  GP g3 = {};
  g3.A = attn_out; g3.Bt = wot; g3.M = 16384; g3.N = 1024; g3.K = 1024;
  g3.outp = (float*)d_out; g3.bo = bo;
  k_gemm2<2><<<64 * 4, 512, 0, stream>>>(g3);
}